// Round 6
// baseline (390.008 us; speedup 1.0000x reference)
//
#include <hip/hip_runtime.h>
#include <stdint.h>

#define B_SZ 8192
#define D_SZ 1024
#define L_SZ 64
#define H_SZ 256

#define BM 256
#define BN 256
#define BK 64

typedef __attribute__((ext_vector_type(8))) __bf16 bf16x8;
typedef __attribute__((ext_vector_type(16))) float f32x16;

typedef __attribute__((address_space(1))) void as1_void;
typedef __attribute__((address_space(3))) void as3_void;

static __device__ __forceinline__ void gload_lds16(const void* g, void* l) {
    __builtin_amdgcn_global_load_lds((as1_void*)g, (as3_void*)l, 16, 0, 0);
}

static __device__ __forceinline__ unsigned short f2bf(float f) {
    uint32_t u = __builtin_bit_cast(uint32_t, f);
    u += 0x7fffu + ((u >> 16) & 1u);
    return (unsigned short)(u >> 16);
}

// ---------------- prep: x (fp32 [B][D]) -> bf16 ----------------
__global__ void cvt_x_kernel(const float* __restrict__ x, unsigned short* __restrict__ xb) {
    int i = blockIdx.x * blockDim.x + threadIdx.x;
    const float4 v = reinterpret_cast<const float4*>(x)[i];
    ushort4 o;
    o.x = f2bf(v.x); o.y = f2bf(v.y); o.z = f2bf(v.z); o.w = f2bf(v.w);
    reinterpret_cast<ushort4*>(xb)[i] = o;
}

// ------- prep: W1 (fp32 [L][D][H]) -> W1T bf16 [L][H][D] -------
__global__ void transpose_w1_kernel(const float* __restrict__ w1, unsigned short* __restrict__ w1t) {
    __shared__ float tile[64][65];
    int b = blockIdx.x;
    int l  = b >> 6;
    int dt = (b >> 2) & 15;
    int ht = b & 3;
    int tx = threadIdx.x & 63;
    int ty = threadIdx.x >> 6;
    const float* src = w1 + (size_t)l * (D_SZ * H_SZ);
    #pragma unroll
    for (int r = 0; r < 64; r += 4)
        tile[r + ty][tx] = src[(size_t)(dt * 64 + r + ty) * H_SZ + ht * 64 + tx];
    __syncthreads();
    unsigned short* dst = w1t + (size_t)l * (H_SZ * D_SZ);
    #pragma unroll
    for (int r = 0; r < 64; r += 4)
        dst[(size_t)(ht * 64 + r + ty) * D_SZ + dt * 64 + tx] = f2bf(tile[tx][r + ty]);
}

// -------- fused label-wise FFN GEMM, 256x256, 8-phase, 32x32x16 MFMA --------
// grid: (B/256)*L = 2048 blocks, 512 threads (8 waves, 2M x 4N).
// R2-proven staging skeleton (stage slots + counted vmcnt identical); B-reads
// all in P0/P1 so no region is read after its restage begins (R5's race fixed).

#define SBAR asm volatile("s_barrier" ::: "memory")
#define VMW(n) asm volatile("s_waitcnt vmcnt(" #n ")" ::: "memory")

// A frag, k-step ks (0..3): row = wr*128 + m*32 + rl32; k-granule = ks*2 + hi
#define DS_READ_A_K(c, ks) do { \
    _Pragma("unroll") for (int m = 0; m < 4; ++m) { \
        const int rowh = m * 32 + rl32; \
        const int slot = ((ks) * 2 + hi) ^ (rowh & 7); \
        af[m] = *reinterpret_cast<const bf16x8*>( \
            reinterpret_cast<const char*>(&ldsAB[c][0][wr][0]) + rowh * 128 + slot * 16); \
    } } while(0)

// B frag, one k-step: cols wc*64 + n*32 + rl32
#define DS_READ_B_KS(c, ks) do { \
    _Pragma("unroll") for (int n = 0; n < 2; ++n) { \
        const int rowb = wc * 64 + n * 32 + rl32; \
        const int bh = rowb >> 7; \
        const int rowh = rowb & 127; \
        const int slot = ((ks) * 2 + hi) ^ (rowh & 7); \
        bfr[n][ks] = *reinterpret_cast<const bf16x8*>( \
            reinterpret_cast<const char*>(&ldsAB[c][1][bh][0]) + rowh * 128 + slot * 16); \
    } } while(0)

// one k-step: 8 MFMA (4m x 2n); af holds this k-step's A
#define MFMA_K(ks) do { \
    __builtin_amdgcn_s_setprio(1); \
    _Pragma("unroll") for (int m = 0; m < 4; ++m) \
    _Pragma("unroll") for (int n = 0; n < 2; ++n) \
        acc[m][n] = __builtin_amdgcn_mfma_f32_32x32x16_bf16( \
            af[m], bfr[n][ks], acc[m][n], 0, 0, 0); \
    __builtin_amdgcn_s_setprio(0); } while(0)

#define STAGE_A(t, h) do { \
    gload_lds16(aSrc[h][0] + (size_t)(t)*BK, &ldsAB[(t)&1][0][h][(wid*64)*8]); \
    gload_lds16(aSrc[h][1] + (size_t)(t)*BK, &ldsAB[(t)&1][0][h][(512 + wid*64)*8]); } while(0)

#define STAGE_B(t, h) do { \
    gload_lds16(bSrc[h][0] + (size_t)(t)*BK, &ldsAB[(t)&1][1][h][(wid*64)*8]); \
    gload_lds16(bSrc[h][1] + (size_t)(t)*BK, &ldsAB[(t)&1][1][h][(512 + wid*64)*8]); } while(0)

__global__ __launch_bounds__(512, 2) void ffn_gemm_kernel(
    const unsigned short* __restrict__ xb,    // bf16 [B][D]
    const unsigned short* __restrict__ w1t,   // bf16 [L][H][D]
    const float* __restrict__ b1,             // [L][H]
    const float* __restrict__ w2,             // [L][H]
    const float* __restrict__ b2,             // [L]
    float* __restrict__ out)                  // f32 [B][L]
{
    // [dbuf][A=0/B=1][half][128 rows * 64 K] bf16 = 128 KiB
    __shared__ unsigned short ldsAB[2][2][2][128 * 64];
    __shared__ float partLds[4][256];

    // bijective XCD swizzle (2048 % 8 == 0)
    const int bid = blockIdx.x;
    const int wg  = ((bid & 7) << 8) + (bid >> 3);
    const int l   = wg >> 5;
    const int m0  = (wg & 31) * BM;

    const int tid  = threadIdx.x;
    const int wid  = tid >> 6;
    const int lane = tid & 63;
    const int wr   = wid >> 2;    // 0..1
    const int wc   = wid & 3;     // 0..3
    const int rl32 = lane & 31;
    const int hi   = lane >> 5;   // 0..1

    // Pre-swizzled global sources (rule #21)
    const unsigned short* aSrc[2][2];
    const unsigned short* bSrc[2][2];
    #pragma unroll
    for (int h = 0; h < 2; ++h)
        #pragma unroll
        for (int c2 = 0; c2 < 2; ++c2) {
            const int q  = c2 * 512 + tid;
            const int r  = q >> 3;
            const int kg = (q & 7) ^ (r & 7);
            aSrc[h][c2] = xb  + (size_t)(m0 + h * 128 + r) * D_SZ + kg * 8;
            bSrc[h][c2] = w1t + ((size_t)l * H_SZ + h * 128 + r) * D_SZ + kg * 8;
        }

    // epilogue constants hoisted
    float b1v[2], w2v[2];
    #pragma unroll
    for (int n = 0; n < 2; ++n) {
        const int col = wc * 64 + n * 32 + rl32;
        b1v[n] = b1[l * H_SZ + col];
        w2v[n] = w2[l * H_SZ + col];
    }
    const float b2v = b2[l];

    f32x16 acc[4][2];
    #pragma unroll
    for (int m = 0; m < 4; ++m)
        #pragma unroll
        for (int n = 0; n < 2; ++n)
            #pragma unroll
            for (int r = 0; r < 16; ++r)
                acc[m][n][r] = 0.f;

    bf16x8 af[4], bfr[2][4];

    // Prologue: B(0), A(0), B(1) = 12 loads; leave B(1)'s 4 in flight.
    STAGE_B(0, 0); STAGE_B(0, 1);
    STAGE_A(0, 0); STAGE_A(0, 1);
    STAGE_B(1, 0); STAGE_B(1, 1);
    VMW(4);
    SBAR;

    // Main loop. Hazard invariant (R2): all reads of a buffer region complete
    // (barrier-separated) BEFORE that region is restaged; staged data is only
    // read after a vmcnt wait proves it landed.
    #pragma unroll 1
    for (int i = 0; i < 7; ++i) {
        const int t1 = 2 * i + 1, t2 = 2 * i + 2, t3 = 2 * i + 3;
        // tile 2i (buf 0): B reads done in P0/P1, B-buf0 restaged P2/P3
        DS_READ_B_KS(0, 0); DS_READ_B_KS(0, 1); DS_READ_A_K(0, 0); STAGE_A(t1, 0); SBAR; MFMA_K(0); SBAR;
        DS_READ_B_KS(0, 2); DS_READ_B_KS(0, 3); DS_READ_A_K(0, 1); STAGE_A(t1, 1); SBAR; MFMA_K(1); SBAR;
        DS_READ_A_K(0, 2);                                         STAGE_B(t2, 0); SBAR; MFMA_K(2); SBAR;
        DS_READ_A_K(0, 3);                                         STAGE_B(t2, 1); SBAR; MFMA_K(3); VMW(4); SBAR;
        // tile 2i+1 (buf 1)
        DS_READ_B_KS(1, 0); DS_READ_B_KS(1, 1); DS_READ_A_K(1, 0); STAGE_A(t2, 0); SBAR; MFMA_K(0); SBAR;
        DS_READ_B_KS(1, 2); DS_READ_B_KS(1, 3); DS_READ_A_K(1, 1); STAGE_A(t2, 1); SBAR; MFMA_K(1); SBAR;
        DS_READ_A_K(1, 2);                                         STAGE_B(t3, 0); SBAR; MFMA_K(2); SBAR;
        DS_READ_A_K(1, 3);                                         STAGE_B(t3, 1); SBAR; MFMA_K(3); VMW(4); SBAR;
    }
    // Tail (tiles 14, 15): only A(15) left to stage; VMW(0) once at P3.
    DS_READ_B_KS(0, 0); DS_READ_B_KS(0, 1); DS_READ_A_K(0, 0); STAGE_A(15, 0); SBAR; MFMA_K(0); SBAR;
    DS_READ_B_KS(0, 2); DS_READ_B_KS(0, 3); DS_READ_A_K(0, 1); STAGE_A(15, 1); SBAR; MFMA_K(1); SBAR;
    DS_READ_A_K(0, 2);                                                          SBAR; MFMA_K(2); SBAR;
    DS_READ_A_K(0, 3);                                                          SBAR; MFMA_K(3); VMW(0); SBAR;
    DS_READ_B_KS(1, 0); DS_READ_B_KS(1, 1); DS_READ_A_K(1, 0);                  SBAR; MFMA_K(0); SBAR;
    DS_READ_B_KS(1, 2); DS_READ_B_KS(1, 3); DS_READ_A_K(1, 1);                  SBAR; MFMA_K(1); SBAR;
    DS_READ_A_K(1, 2);                                                          SBAR; MFMA_K(2); SBAR;
    DS_READ_A_K(1, 3);                                                          SBAR; MFMA_K(3); SBAR;

    // ---- fused epilogue: out[row, l] = sum_h relu(C + b1)*w2 + b2 ----
    // C/D layout (32x32, m74/m101): col=lane&31, row=(r&3)+8*(r>>2)+4*hi
    #pragma unroll
    for (int m = 0; m < 4; ++m) {
        #pragma unroll
        for (int r = 0; r < 16; ++r) {
            float v0 = fmaxf(acc[m][0][r] + b1v[0], 0.f);
            float v1 = fmaxf(acc[m][1][r] + b1v[1], 0.f);
            float p = v0 * w2v[0] + v1 * w2v[1];
            p += __shfl_xor(p, 1);
            p += __shfl_xor(p, 2);
            p += __shfl_xor(p, 4);
            p += __shfl_xor(p, 8);
            p += __shfl_xor(p, 16);
            if (rl32 == 0)
                partLds[wc][wr * 128 + m * 32 + (r & 3) + 8 * (r >> 2) + 4 * hi] = p;
        }
    }
    __syncthreads();
    if (tid < BM) {
        float s = b2v;
        #pragma unroll
        for (int w = 0; w < 4; ++w) s += partLds[w][tid];
        out[(size_t)(m0 + tid) * L_SZ + l] = s;
    }
}

extern "C" void kernel_launch(void* const* d_in, const int* in_sizes, int n_in,
                              void* d_out, int out_size, void* d_ws, size_t ws_size,
                              hipStream_t stream) {
    const float* x  = (const float*)d_in[0];
    const float* W1 = (const float*)d_in[1];
    const float* b1 = (const float*)d_in[2];
    const float* W2 = (const float*)d_in[3];
    const float* b2 = (const float*)d_in[4];
    float* out = (float*)d_out;

    unsigned short* xb  = (unsigned short*)d_ws;                 // 16 MB
    unsigned short* w1t = xb + (size_t)B_SZ * D_SZ;              // 32 MB

    cvt_x_kernel<<<(B_SZ * D_SZ / 4) / 256, 256, 0, stream>>>(x, xb);
    transpose_w1_kernel<<<L_SZ * 16 * 4, 256, 0, stream>>>(W1, w1t);
    ffn_gemm_kernel<<<(B_SZ / BM) * L_SZ, 512, 0, stream>>>(xb, w1t, b1, W2, b2, out);
}

// Round 7
// 316.803 us; speedup vs baseline: 1.2311x; 1.2311x over previous
//
#include <hip/hip_runtime.h>
#include <stdint.h>

#define B_SZ 8192
#define D_SZ 1024
#define L_SZ 64
#define H_SZ 256

#define BM 128
#define BN 256
#define BK 32
#define NTILE (D_SZ / BK)   // 32

typedef __attribute__((ext_vector_type(8))) __bf16 bf16x8;
typedef __attribute__((ext_vector_type(4))) float f32x4;

typedef __attribute__((address_space(1))) void as1_void;
typedef __attribute__((address_space(3))) void as3_void;

static __device__ __forceinline__ void gload_lds16(const void* g, void* l) {
    __builtin_amdgcn_global_load_lds((as1_void*)g, (as3_void*)l, 16, 0, 0);
}

static __device__ __forceinline__ unsigned short f2bf(float f) {
    uint32_t u = __builtin_bit_cast(uint32_t, f);
    u += 0x7fffu + ((u >> 16) & 1u);
    return (unsigned short)(u >> 16);
}

// ---------------- prep: x (fp32 [B][D]) -> bf16 ----------------
__global__ void cvt_x_kernel(const float* __restrict__ x, unsigned short* __restrict__ xb) {
    int i = blockIdx.x * blockDim.x + threadIdx.x;
    const float4 v = reinterpret_cast<const float4*>(x)[i];
    ushort4 o;
    o.x = f2bf(v.x); o.y = f2bf(v.y); o.z = f2bf(v.z); o.w = f2bf(v.w);
    reinterpret_cast<ushort4*>(xb)[i] = o;
}

// ------- prep: W1 (fp32 [L][D][H]) -> W1T bf16 [L][H][D] -------
__global__ void transpose_w1_kernel(const float* __restrict__ w1, unsigned short* __restrict__ w1t) {
    __shared__ float tile[64][65];
    int b = blockIdx.x;
    int l  = b >> 6;
    int dt = (b >> 2) & 15;
    int ht = b & 3;
    int tx = threadIdx.x & 63;
    int ty = threadIdx.x >> 6;
    const float* src = w1 + (size_t)l * (D_SZ * H_SZ);
    #pragma unroll
    for (int r = 0; r < 64; r += 4)
        tile[r + ty][tx] = src[(size_t)(dt * 64 + r + ty) * H_SZ + ht * 64 + tx];
    __syncthreads();
    unsigned short* dst = w1t + (size_t)l * (H_SZ * D_SZ);
    #pragma unroll
    for (int r = 0; r < 64; r += 4)
        dst[(size_t)(ht * 64 + r + ty) * D_SZ + dt * 64 + tx] = f2bf(tile[tx][r + ty]);
}

// ---- fused label-wise FFN GEMM: 128x256, BK=32, 3-deep ring, 2 blocks/CU ----
// grid: (B/128)*L = 4096 blocks, 512 threads (8 waves, 2M x 4N).
// 16x16x32 core (R2-proven fragment/swizzle family). Counted vmcnt(6): two
// tiles always in flight; co-resident second block hides barrier stalls.

#define SBAR asm volatile("s_barrier" ::: "memory")
#define VMW(n) asm volatile("s_waitcnt vmcnt(" #n ")" ::: "memory")

// stage tile t into ring buffer bi (literal): 3 loads/thread (A x1, B x2)
#define STAGE(t, bi) do { \
    const size_t koff = (size_t)(t) * BK; \
    gload_lds16(aSrcG + koff,    (char*)&ldsA[bi][0] + tid * 16); \
    gload_lds16(bSrcG0 + koff,   (char*)&ldsB[bi][0] + tid * 16); \
    gload_lds16(bSrcG1 + koff,   (char*)&ldsB[bi][0] + 8192 + tid * 16); \
} while(0)

// compute one K-tile from ring buffer bi: 8 ds_read_b128 + 16 MFMA per wave
#define COMPUTE(bi) do { \
    bf16x8 af[4], bv[4]; \
    _Pragma("unroll") for (int m = 0; m < 4; ++m) { \
        const int row = wr * 64 + m * 16 + rl; \
        const int slot = gq ^ ((row >> 1) & 3); \
        af[m] = *reinterpret_cast<const bf16x8*>( \
            reinterpret_cast<const char*>(&ldsA[bi][0]) + row * 64 + slot * 16); \
    } \
    _Pragma("unroll") for (int n = 0; n < 4; ++n) { \
        const int row = wc * 64 + n * 16 + rl; \
        const int slot = gq ^ ((row >> 1) & 3); \
        bv[n] = *reinterpret_cast<const bf16x8*>( \
            reinterpret_cast<const char*>(&ldsB[bi][0]) + row * 64 + slot * 16); \
    } \
    __builtin_amdgcn_s_setprio(1); \
    _Pragma("unroll") for (int m = 0; m < 4; ++m) \
    _Pragma("unroll") for (int n = 0; n < 4; ++n) \
        acc[m][n] = __builtin_amdgcn_mfma_f32_16x16x32_bf16(af[m], bv[n], acc[m][n], 0, 0, 0); \
    __builtin_amdgcn_s_setprio(0); \
} while(0)

__global__ __launch_bounds__(512, 4) void ffn_gemm_kernel(
    const unsigned short* __restrict__ xb,    // bf16 [B][D]
    const unsigned short* __restrict__ w1t,   // bf16 [L][H][D]
    const float* __restrict__ b1,             // [L][H]
    const float* __restrict__ w2,             // [L][H]
    const float* __restrict__ b2,             // [L]
    float* __restrict__ out)                  // f32 [B][L]
{
    __shared__ unsigned short ldsA[3][BM * BK];   // 3 x 8 KB
    __shared__ unsigned short ldsB[3][BN * BK];   // 3 x 16 KB
    __shared__ float partLds[2][64][4];           // 2 KB  -> 74 KB total

    // bijective XCD swizzle (4096 % 8 == 0): 512 contiguous wgs per XCD;
    // 64 consecutive wgs share one label -> B panel L2-hot per XCD.
    const int bid = blockIdx.x;
    const int wg  = ((bid & 7) << 9) + (bid >> 3);
    const int l   = wg >> 6;
    const int m0  = (wg & 63) * BM;

    const int tid  = threadIdx.x;
    const int wid  = tid >> 6;
    const int lane = tid & 63;
    const int wr   = wid >> 2;   // 0..1
    const int wc   = wid & 3;    // 0..3
    const int gq   = lane >> 4;  // 0..3 (k-granule)
    const int rl   = lane & 15;

    // Pre-swizzled global sources (rule #21). 64-B rows, 4 slots/row:
    // granule g stored at slot g ^ ((row>>1)&3)  (all-8-distinct bank quads
    // per 8 rows; 2 lanes/quad over 16-lane groups = free, R2-class).
    const int arow = tid >> 2;
    const int aslt = tid & 3;
    const unsigned short* aSrcG =
        xb + (size_t)(m0 + arow) * D_SZ + (aslt ^ ((arow >> 1) & 3)) * 8;
    const int brow0 = tid >> 2;
    const unsigned short* bSrcG0 =
        w1t + ((size_t)l * H_SZ + brow0) * D_SZ + ((tid & 3) ^ ((brow0 >> 1) & 3)) * 8;
    const int q1 = 512 + tid;
    const int brow1 = q1 >> 2;
    const unsigned short* bSrcG1 =
        w1t + ((size_t)l * H_SZ + brow1) * D_SZ + ((q1 & 3) ^ ((brow1 >> 1) & 3)) * 8;

    f32x4 acc[4][4];
    #pragma unroll
    for (int m = 0; m < 4; ++m)
        #pragma unroll
        for (int n = 0; n < 4; ++n) {
            acc[m][n][0] = 0.f; acc[m][n][1] = 0.f;
            acc[m][n][2] = 0.f; acc[m][n][3] = 0.f;
        }

    // Prologue: tiles 0,1 staged; wait tile 0 (3 newest = tile 1 stay in flight)
    STAGE(0, 0); STAGE(1, 1);
    VMW(3);
    SBAR;

    // Main: iter t stages tile t+2 into buf (t+2)%3, VMW(6) forces tile t
    // landed (newest 6 = tiles t+1, t+2), computes buf t%3. Closing SBAR
    // makes this iter's reads complete before next iter's stage overwrites.
    #pragma unroll 1
    for (int tt = 0; tt < 30; tt += 3) {
        STAGE(tt + 2, 2); VMW(6); SBAR; COMPUTE(0); SBAR;
        STAGE(tt + 3, 0); VMW(6); SBAR; COMPUTE(1); SBAR;
        STAGE(tt + 4, 1); VMW(6); SBAR; COMPUTE(2); SBAR;
    }
    // Tail: tiles 30 (buf 0), 31 (buf 1); nothing left to stage.
    VMW(3); SBAR; COMPUTE(0); SBAR;
    VMW(0); SBAR; COMPUTE(1);

    // ---- fused epilogue: out[row, l] = sum_h relu(C + b1)*w2 + b2 ----
    float b1v[4], w2v[4];
    #pragma unroll
    for (int n = 0; n < 4; ++n) {
        const int col = wc * 64 + n * 16 + rl;
        b1v[n] = b1[l * H_SZ + col];
        w2v[n] = w2[l * H_SZ + col];
    }
    const float b2v = b2[l];
    #pragma unroll
    for (int m = 0; m < 4; ++m) {
        #pragma unroll
        for (int r = 0; r < 4; ++r) {
            float p = 0.f;
            #pragma unroll
            for (int n = 0; n < 4; ++n) {
                float v = acc[m][n][r] + b1v[n];
                v = fmaxf(v, 0.f);
                p += v * w2v[n];
            }
            p += __shfl_xor(p, 1);
            p += __shfl_xor(p, 2);
            p += __shfl_xor(p, 4);
            p += __shfl_xor(p, 8);
            if (rl == 0)
                partLds[wr][m * 16 + gq * 4 + r][wc] = p;
        }
    }
    __syncthreads();
    if (tid < BM) {
        float s = b2v;
        #pragma unroll
        for (int w = 0; w < 4; ++w) s += partLds[tid >> 6][tid & 63][w];
        out[(size_t)(m0 + tid) * L_SZ + l] = s;
    }
}

extern "C" void kernel_launch(void* const* d_in, const int* in_sizes, int n_in,
                              void* d_out, int out_size, void* d_ws, size_t ws_size,
                              hipStream_t stream) {
    const float* x  = (const float*)d_in[0];
    const float* W1 = (const float*)d_in[1];
    const float* b1 = (const float*)d_in[2];
    const float* W2 = (const float*)d_in[3];
    const float* b2 = (const float*)d_in[4];
    float* out = (float*)d_out;

    unsigned short* xb  = (unsigned short*)d_ws;                 // 16 MB
    unsigned short* w1t = xb + (size_t)B_SZ * D_SZ;              // 32 MB

    cvt_x_kernel<<<(B_SZ * D_SZ / 4) / 256, 256, 0, stream>>>(x, xb);
    transpose_w1_kernel<<<L_SZ * 16 * 4, 256, 0, stream>>>(W1, w1t);
    ffn_gemm_kernel<<<(B_SZ / BM) * L_SZ, 512, 0, stream>>>(xb, w1t, b1, W2, b2, out);
}